// Round 1
// baseline (124.788 us; speedup 1.0000x reference)
//
#include <hip/hip_runtime.h>

#define IN_DIM  4096
#define OUT_DIM 11008
#define NSUB    1376
#define KSQ     256
#define DSUB    8
#define BATCH   32

#define DTILE   16                   // subspaces per block -> N tile = 128
#define NTILE   128
#define KC      128                  // k elements staged per chunk
#define KSPLIT  8                    // k-blocks in grid (was 16)
#define KPB     (IN_DIM / KSPLIT)    // 512 k per block
#define NCHUNK  (KPB / KC)           // 4 chunks per block
#define NBLK    (OUT_DIM / NTILE)    // 86

typedef unsigned short ushort_t;
typedef unsigned int   uint_t;
typedef __attribute__((ext_vector_type(8))) short bf16x8;
typedef __attribute__((ext_vector_type(4))) float f32x4;

// LDS strides (elements). 136 ushorts = 68 dwords (≡4 mod 32 banks): balanced b128 access.
#define SW_STRIDE 136
#define SX_STRIDE 136
#define SI_STRIDE 132

// workspace layout
#define VEC_N   (NSUB * KSQ * DSUB)          // 2818048 floats
#define XBF_OFF 5636096                      // bytes: VEC_N * 2
#define PREP_V  (VEC_N / 2)                  // 1409024 uint (2 bf16 each)
#define PREP_X  (BATCH * IN_DIM / 2)         // 65536
#define PREP_O  (BATCH * OUT_DIM)            // 352256
#define PREP_N  (PREP_V + PREP_X + PREP_O)   // 1826816 = 7136 * 256

__device__ __forceinline__ ushort_t f2bf(float f) {
    union { float f; uint_t u; } a; a.f = f;
    uint_t u = a.u;
    u += 0x7fffu + ((u >> 16) & 1u);   // round-to-nearest-even
    return (ushort_t)(u >> 16);
}

__global__ __launch_bounds__(256) void pq_prep(
    const float* __restrict__ x, const float* __restrict__ vecs,
    const float* __restrict__ bias,
    uint_t* __restrict__ vbf, uint_t* __restrict__ xbf, float* __restrict__ out)
{
    int tid = blockIdx.x * 256 + threadIdx.x;
    if (tid < PREP_V) {
        float2 v = ((const float2*)vecs)[tid];
        vbf[tid] = (uint_t)f2bf(v.x) | ((uint_t)f2bf(v.y) << 16);
    } else if (tid < PREP_V + PREP_X) {
        int i = tid - PREP_V;
        float2 v = ((const float2*)x)[i];
        xbf[i] = (uint_t)f2bf(v.x) | ((uint_t)f2bf(v.y) << 16);
    } else {
        int i = tid - (PREP_V + PREP_X);
        out[i] = bias[i % OUT_DIM];
    }
}

// ---- pq_main helpers -------------------------------------------------------

__device__ __forceinline__ void load_chunk(
    const int* __restrict__ idx, const ushort_t* __restrict__ xbf,
    int i0, int d0, int t, int (&ireg)[8], uint4 (&xreg)[2])
{
    #pragma unroll
    for (int p = 0; p < 8; ++p) {
        int f = p * 256 + t, ii = f >> 4, dd = f & 15;
        ireg[p] = idx[(size_t)(i0 + ii) * NSUB + (d0 + dd)];
    }
    #pragma unroll
    for (int p = 0; p < 2; ++p) {
        int f = p * 256 + t, b = f >> 4, q = f & 15;
        xreg[p] = ((const uint4*)xbf)[b * (IN_DIM / 8) + i0 / 8 + q];
    }
}

__device__ __forceinline__ void commit_chunk(
    int* sIbuf, ushort_t* sXbuf, int t,
    const int (&ireg)[8], const uint4 (&xreg)[2])
{
    #pragma unroll
    for (int p = 0; p < 8; ++p) {
        int f = p * 256 + t, ii = f >> 4, dd = f & 15;
        sIbuf[dd * SI_STRIDE + ii] = ireg[p];
    }
    #pragma unroll
    for (int p = 0; p < 2; ++p) {
        int f = p * 256 + t, b = f >> 4, q = f & 15;
        *(uint4*)&sXbuf[b * SX_STRIDE + q * 8] = xreg[p];
    }
}

__device__ __forceinline__ void mfma_chunk(
    const ushort_t* __restrict__ sx, const ushort_t* __restrict__ sw,
    f32x4 (&acc)[2][2], int l15, int l4, int wave)
{
    #pragma unroll
    for (int kq = 0; kq < KC / 32; ++kq) {
        bf16x8 A[2], B[2];
        #pragma unroll
        for (int mt = 0; mt < 2; ++mt)
            A[mt] = *(const bf16x8*)&sx[(mt * 16 + l15) * SX_STRIDE + kq * 32 + l4 * 8];
        #pragma unroll
        for (int nt = 0; nt < 2; ++nt)
            B[nt] = *(const bf16x8*)&sw[(wave * 32 + nt * 16 + l15) * SW_STRIDE + kq * 32 + l4 * 8];
        #pragma unroll
        for (int mt = 0; mt < 2; ++mt)
            #pragma unroll
            for (int nt = 0; nt < 2; ++nt)
                acc[mt][nt] = __builtin_amdgcn_mfma_f32_16x16x32_bf16(
                    A[mt], B[nt], acc[mt][nt], 0, 0, 0);
    }
}

// ---- main kernel -----------------------------------------------------------
//
// Pipeline per chunk c (2 barriers):
//   BAR_A
//   G: gathers for chunk c (from sI[c&1]) -> q regs           (long latency)
//   M: MFMA chunk c-1 (sW wave-local, sX[(c-1)&1])            (hides G latency)
//   BAR_B
//   T: transpose q -> sW; commit regs (chunk c+1) -> sI/sX[(c+1)&1];
//      issue global loads for chunk c+2 -> regs               (full-iter distance)
//
// sW is WAVE-LOCAL: wave w writes rows [32w,32w+32) in T and reads the same
// rows in M (per-wave in-order LDS) -> no barrier needed for sW itself.

__global__ __launch_bounds__(256) void pq_main(
    const ushort_t* __restrict__ xbf, const uint4* __restrict__ vbf,
    const int* __restrict__ idx, float* __restrict__ out)
{
    __shared__ ushort_t sW[NTILE * SW_STRIDE];       // 34.0 KB, single (wave-local)
    __shared__ ushort_t sX[2][BATCH * SX_STRIDE];    // 17.0 KB, double-buffered
    __shared__ int      sI[2][DTILE * SI_STRIDE];    // 16.5 KB, double-buffered

    const int t    = threadIdx.x;
    const int nblk = blockIdx.x;        // 0..85
    const int kblk = blockIdx.y;        // 0..7
    const int d0   = nblk * DTILE;
    const int kbase = kblk * KPB;

    const int wave = t >> 6;
    const int lane = t & 63;
    const int l15  = lane & 15;
    const int l4   = lane >> 4;

    const int gd = t >> 4;              // gather: subspace 0..15
    const int go = t & 15;              // gather: k-oct 0..15

    f32x4 acc[2][2];
    #pragma unroll
    for (int i = 0; i < 2; ++i)
        #pragma unroll
        for (int j = 0; j < 2; ++j)
            acc[i][j] = (f32x4)0.0f;

    int   ireg[8];
    uint4 xreg[2];

    // prologue: chunk 0 -> LDS buf 0; then preload chunk 1 into regs
    load_chunk(idx, xbf, kbase, d0, t, ireg, xreg);
    commit_chunk(&sI[0][0], &sX[0][0], t, ireg, xreg);
    load_chunk(idx, xbf, kbase + KC, d0, t, ireg, xreg);

    #pragma unroll
    for (int c = 0; c < NCHUNK; ++c) {
        __syncthreads();   // BAR_A: sI/sX commits visible to all waves

        // --- G: issue gathers for chunk c (8 bf16 codewords, one uint4 each)
        const int* sic = &sI[c & 1][0];
        int4 ka = *(const int4*)&sic[gd * SI_STRIDE + go * 8];
        int4 kb = *(const int4*)&sic[gd * SI_STRIDE + go * 8 + 4];
        uint4 q[8];
        q[0] = vbf[(d0 + gd) * KSQ + ka.x];
        q[1] = vbf[(d0 + gd) * KSQ + ka.y];
        q[2] = vbf[(d0 + gd) * KSQ + ka.z];
        q[3] = vbf[(d0 + gd) * KSQ + ka.w];
        q[4] = vbf[(d0 + gd) * KSQ + kb.x];
        q[5] = vbf[(d0 + gd) * KSQ + kb.y];
        q[6] = vbf[(d0 + gd) * KSQ + kb.z];
        q[7] = vbf[(d0 + gd) * KSQ + kb.w];

        // --- M: MFMA for the previous chunk (covers gather latency)
        if (c > 0)
            mfma_chunk(&sX[(c - 1) & 1][0], sW, acc, l15, l4, wave);

        __syncthreads();   // BAR_B: M-phase sX reads done before T-phase writes

        // --- T: 8x8 bf16 transpose via v_perm, write k-contiguous b128s to sW[n][k]
        #pragma unroll
        for (int j = 0; j < 8; ++j) {
            const uint_t sel = (j & 1) ? 0x07060302u : 0x05040100u;
            uint_t c0 = (j >> 1) == 0 ? q[0].x : (j >> 1) == 1 ? q[0].y : (j >> 1) == 2 ? q[0].z : q[0].w;
            uint_t c1 = (j >> 1) == 0 ? q[1].x : (j >> 1) == 1 ? q[1].y : (j >> 1) == 2 ? q[1].z : q[1].w;
            uint_t c2 = (j >> 1) == 0 ? q[2].x : (j >> 1) == 1 ? q[2].y : (j >> 1) == 2 ? q[2].z : q[2].w;
            uint_t c3 = (j >> 1) == 0 ? q[3].x : (j >> 1) == 1 ? q[3].y : (j >> 1) == 2 ? q[3].z : q[3].w;
            uint_t c4 = (j >> 1) == 0 ? q[4].x : (j >> 1) == 1 ? q[4].y : (j >> 1) == 2 ? q[4].z : q[4].w;
            uint_t c5 = (j >> 1) == 0 ? q[5].x : (j >> 1) == 1 ? q[5].y : (j >> 1) == 2 ? q[5].z : q[5].w;
            uint_t c6 = (j >> 1) == 0 ? q[6].x : (j >> 1) == 1 ? q[6].y : (j >> 1) == 2 ? q[6].z : q[6].w;
            uint_t c7 = (j >> 1) == 0 ? q[7].x : (j >> 1) == 1 ? q[7].y : (j >> 1) == 2 ? q[7].z : q[7].w;
            uint4 wv;
            wv.x = __builtin_amdgcn_perm(c1, c0, sel);
            wv.y = __builtin_amdgcn_perm(c3, c2, sel);
            wv.z = __builtin_amdgcn_perm(c5, c4, sel);
            wv.w = __builtin_amdgcn_perm(c7, c6, sel);
            *(uint4*)&sW[(gd * 8 + j) * SW_STRIDE + go * 8] = wv;
        }

        // --- commit chunk c+1 regs, then issue loads for chunk c+2
        if (c + 1 < NCHUNK)
            commit_chunk(&sI[(c + 1) & 1][0], &sX[(c + 1) & 1][0], t, ireg, xreg);
        if (c + 2 < NCHUNK)
            load_chunk(idx, xbf, kbase + (c + 2) * KC, d0, t, ireg, xreg);
    }

    // --- final MFMA for the last chunk (sW wave-local: no barrier needed)
    mfma_chunk(&sX[(NCHUNK - 1) & 1][0], sW, acc, l15, l4, wave);

    // --- epilogue: accumulate into out (pre-initialized with bias)
    #pragma unroll
    for (int mt = 0; mt < 2; ++mt)
        #pragma unroll
        for (int nt = 0; nt < 2; ++nt)
            #pragma unroll
            for (int r = 0; r < 4; ++r) {
                int row = mt * 16 + l4 * 4 + r;                       // batch
                int col = nblk * NTILE + wave * 32 + nt * 16 + l15;   // out col
                atomicAdd(&out[(size_t)row * OUT_DIM + col], acc[mt][nt][r]);
            }
}

extern "C" void kernel_launch(void* const* d_in, const int* in_sizes, int n_in,
                              void* d_out, int out_size, void* d_ws, size_t ws_size,
                              hipStream_t stream) {
    const float* x    = (const float*)d_in[0];
    const float* vecs = (const float*)d_in[1];
    const float* bias = (const float*)d_in[2];
    const int*   idx  = (const int*)d_in[3];
    float* out = (float*)d_out;

    uint_t* vbf = (uint_t*)d_ws;                           // 5.6 MB bf16 codebook
    uint_t* xbf = (uint_t*)((char*)d_ws + XBF_OFF);        // 256 KB bf16 x

    pq_prep<<<PREP_N / 256, 256, 0, stream>>>(x, vecs, bias, vbf, xbf, out);
    dim3 grid(NBLK, KSPLIT);
    pq_main<<<grid, 256, 0, stream>>>((const ushort_t*)xbf, (const uint4*)vbf,
                                      idx, out);
}

// Round 2
// 116.053 us; speedup vs baseline: 1.0753x; 1.0753x over previous
//
#include <hip/hip_runtime.h>

#define IN_DIM  4096
#define OUT_DIM 11008
#define NSUB    1376
#define KSQ     256
#define DSUB    8
#define BATCH   32

#define DTILE   8                    // subspaces per block
#define NTILE   64                   // = DTILE * DSUB output cols per block
#define KC      64                   // k per chunk
#define KSPLIT  16                   // k-blocks in grid
#define KPB     (IN_DIM / KSPLIT)    // 256
#define NCHUNK  (KPB / KC)           // 4
#define NBLK    (OUT_DIM / NTILE)    // 172

typedef unsigned short ushort_t;
typedef unsigned int   uint_t;
typedef unsigned char  uchar_t;
typedef __attribute__((ext_vector_type(8))) short bf16x8;
typedef __attribute__((ext_vector_type(4))) float f32x4;

// workspace layout (bytes)
#define VEC_N    (NSUB * KSQ * DSUB)              // 2818048 floats
#define XBF_OFF  (VEC_N * 2)                      // 5636096  : xbf (bf16 x)
#define IDXT_OFF (XBF_OFF + BATCH * IN_DIM * 2)   // 5898240  : idx8T bytes [NSUB][IN_DIM]
#define SLAB_OFF (IDXT_OFF + NSUB * IN_DIM)       // 11534336 : f32 slabs [KSPLIT][BATCH][OUT_DIM]
#define PREP_V   (VEC_N / 2)                      // 1409024 uints (2 bf16 each)
#define PREP_X   (BATCH * IN_DIM / 2)             // 65536
#define PREP_N   (PREP_V + PREP_X)                // 1474560 = 5760 * 256

__device__ __forceinline__ ushort_t f2bf(float f) {
    union { float f; uint_t u; } a; a.f = f;
    uint_t u = a.u;
    u += 0x7fffu + ((u >> 16) & 1u);   // round-to-nearest-even
    return (ushort_t)(u >> 16);
}

// ---- prep 1: bf16-pack codebook + x ---------------------------------------
__global__ __launch_bounds__(256) void pq_prep(
    const float* __restrict__ x, const float* __restrict__ vecs,
    uint_t* __restrict__ vbf, uint_t* __restrict__ xbf)
{
    int tid = blockIdx.x * 256 + threadIdx.x;
    if (tid < PREP_V) {
        float2 v = ((const float2*)vecs)[tid];
        vbf[tid] = (uint_t)f2bf(v.x) | ((uint_t)f2bf(v.y) << 16);
    } else {
        int i = tid - PREP_V;
        float2 v = ((const float2*)x)[i];
        xbf[i] = (uint_t)f2bf(v.x) | ((uint_t)f2bf(v.y) << 16);
    }
}

// ---- prep 2: transpose idx [k][d] int32 -> idx8T [d][k] uint8 -------------
__global__ __launch_bounds__(256) void pq_idxT(
    const int* __restrict__ idx, uchar_t* __restrict__ idx8T)
{
    __shared__ uchar_t sT[32][144];    // 144 = 16-aligned row stride
    const int k0 = blockIdx.x * 128, d0 = blockIdx.y * 32, t = threadIdx.x;
    #pragma unroll
    for (int p = 0; p < 16; ++p) {
        int f = p * 256 + t;           // 0..4095
        int kk = f >> 5, dd = f & 31;
        sT[dd][kk] = (uchar_t)idx[(size_t)(k0 + kk) * NSUB + d0 + dd];
    }
    __syncthreads();
    int dd = t >> 3, seg = t & 7;
    uint4 v = *(const uint4*)&sT[dd][seg * 16];
    *(uint4*)&idx8T[(size_t)(d0 + dd) * IN_DIM + k0 + seg * 16] = v;
}

// ---- main: barrier-free, wave-independent PQ-GEMM -------------------------
//
// Block: 256 thr = 4 waves. Wave w owns 2 subspaces (16 out cols), all 32 m,
// KPB k. Codebook slice staged to wave-local LDS once; gathers are LDS-side.
// A-fragments (x) preloaded to registers for the whole KPB. Dense slab store.
// No __syncthreads anywhere.
__global__ __launch_bounds__(256, 4) void pq_main(
    const ushort_t* __restrict__ xbf, const uint4* __restrict__ vbf4,
    const uchar_t* __restrict__ idx8T, float* __restrict__ slab)
{
    __shared__ uint4  sV4[4 * 512];        // 32 KB: per-wave 2x256 codewords
    __shared__ uint_t sW32[4 * 16 * 32];   //  8 KB: per-wave 16 rows x 64 k bf16 (xor-swizzled)

    const int t    = threadIdx.x;
    const int w    = t >> 6;
    const int lane = t & 63;
    const int nblk = blockIdx.x;           // 0..171
    const int kblk = blockIdx.y;           // 0..15
    const int d0   = nblk * DTILE;
    const int kbase = kblk * KPB;

    const int l15 = lane & 15;
    const int l4  = lane >> 4;
    const int dl  = lane >> 5;             // 0..1 : subspace within wave
    const int q   = lane & 31;             // 0..31 : k-pair within chunk

    // --- stage codebook slice: wave w copies rows (d0+2w, d0+2w+1), 8 KB
    {
        const size_t src0 = (size_t)(d0 + w * 2) * KSQ;   // uint4 units
        #pragma unroll
        for (int p = 0; p < 8; ++p)
            sV4[w * 512 + p * 64 + lane] = vbf4[src0 + p * 64 + lane];
    }

    // --- preload A fragments for the whole KPB (16 frags = 64 VGPR)
    bf16x8 A[2][8];
    #pragma unroll
    for (int mt = 0; mt < 2; ++mt)
        #pragma unroll
        for (int kk = 0; kk < 8; ++kk)
            A[mt][kk] = *(const bf16x8*)
                &xbf[(size_t)(mt * 16 + l15) * IN_DIM + kbase + kk * 32 + l4 * 8];

    f32x4 acc[2];
    acc[0] = (f32x4)0.0f; acc[1] = (f32x4)0.0f;

    const uchar_t* idxrow = idx8T + (size_t)(d0 + w * 2 + dl) * IN_DIM + kbase;
    const int vbase = w * 512 + dl * 256;
    const int Rbase = (w * 16 + dl * 8) * 32;   // dword base of this lane's 8 rows

    #pragma unroll
    for (int c = 0; c < NCHUNK; ++c) {
        // 2 codes (k = c*64 + 2q, +1), 1 coalesced ushort load
        uint_t bb = *(const ushort_t*)&idxrow[c * KC + q * 2];
        uint4 g0 = sV4[vbase + (bb & 255)];
        uint4 g1 = sV4[vbase + (bb >> 8)];

        // transpose 2x8 -> 8 b32 writes; xor-swizzle 16B units with row&7 (=j)
        #pragma unroll
        for (int j = 0; j < 8; ++j) {
            const uint_t sel = (j & 1) ? 0x07060302u : 0x05040100u;
            uint_t a0 = (j >> 1) == 0 ? g0.x : (j >> 1) == 1 ? g0.y : (j >> 1) == 2 ? g0.z : g0.w;
            uint_t a1 = (j >> 1) == 0 ? g1.x : (j >> 1) == 1 ? g1.y : (j >> 1) == 2 ? g1.z : g1.w;
            uint_t wv = __builtin_amdgcn_perm(a1, a0, sel);   // [k even | k odd<<16]
            int dw = ((((q >> 2) ^ j) << 2) | (q & 3));
            sW32[Rbase + j * 32 + dw] = wv;
        }

        // B read (swizzled) + MFMA
        #pragma unroll
        for (int kq = 0; kq < 2; ++kq) {
            int u16 = (kq * 4 + l4) ^ (l15 & 7);
            bf16x8 B = *(const bf16x8*)
                ((const char*)sW32 + (w * 16 + l15) * 128 + u16 * 16);
            #pragma unroll
            for (int mt = 0; mt < 2; ++mt)
                acc[mt] = __builtin_amdgcn_mfma_f32_16x16x32_bf16(
                    A[mt][c * 2 + kq], B, acc[mt], 0, 0, 0);
        }
    }

    // --- dense store to this kblk's slab (no atomics)
    float* sl = slab + (size_t)kblk * BATCH * OUT_DIM;
    const int col = nblk * NTILE + w * 16 + l15;
    #pragma unroll
    for (int mt = 0; mt < 2; ++mt)
        #pragma unroll
        for (int r = 0; r < 4; ++r)
            sl[(size_t)(mt * 16 + l4 * 4 + r) * OUT_DIM + col] = acc[mt][r];
}

// ---- reduce: out = bias + sum_k slabs -------------------------------------
__global__ __launch_bounds__(256) void pq_reduce(
    const float* __restrict__ slab, const float* __restrict__ bias,
    float* __restrict__ out)
{
    int i = blockIdx.x * 256 + threadIdx.x;        // < 88064
    int m = i / (OUT_DIM / 4), n4 = i % (OUT_DIM / 4);
    float4 s = ((const float4*)bias)[n4];
    #pragma unroll
    for (int kb = 0; kb < KSPLIT; ++kb) {
        float4 v = ((const float4*)slab)[(size_t)(kb * BATCH + m) * (OUT_DIM / 4) + n4];
        s.x += v.x; s.y += v.y; s.z += v.z; s.w += v.w;
    }
    ((float4*)out)[(size_t)m * (OUT_DIM / 4) + n4] = s;
}

extern "C" void kernel_launch(void* const* d_in, const int* in_sizes, int n_in,
                              void* d_out, int out_size, void* d_ws, size_t ws_size,
                              hipStream_t stream) {
    const float* x    = (const float*)d_in[0];
    const float* vecs = (const float*)d_in[1];
    const float* bias = (const float*)d_in[2];
    const int*   idx  = (const int*)d_in[3];
    float* out = (float*)d_out;

    uint_t*  vbf   = (uint_t*)d_ws;
    uint_t*  xbf   = (uint_t*)((char*)d_ws + XBF_OFF);
    uchar_t* idx8T = (uchar_t*)((char*)d_ws + IDXT_OFF);
    float*   slab  = (float*)((char*)d_ws + SLAB_OFF);

    pq_prep<<<PREP_N / 256, 256, 0, stream>>>(x, vecs, vbf, xbf);
    pq_idxT<<<dim3(IN_DIM / 128, NSUB / 32), 256, 0, stream>>>(idx, idx8T);
    pq_main<<<dim3(NBLK, KSPLIT), 256, 0, stream>>>(
        (const ushort_t*)xbf, (const uint4*)vbf, idx8T, slab);
    pq_reduce<<<(BATCH * OUT_DIM / 4) / 256, 256, 0, stream>>>(slab, bias, out);
}